// Round 9
// baseline (52.712 us; speedup 1.0000x reference)
//
#include <hip/hip_runtime.h>
#include <math.h>

namespace fc {

typedef float vf2 __attribute__((ext_vector_type(2)));
typedef float vf4 __attribute__((ext_vector_type(4)));

__device__ __forceinline__ vf2 sp(float c) { return vf2{c, c}; }

constexpr float ACT_SCALE = 10.0f;
constexpr float U_HOVER   = 0.515025f;          // -MASS*-9.81/10/1/4
constexpr float INV_MASS  = 1.0f / 2.1f;
constexpr float KM        = 0.025f;
constexpr float TAUC      = 0.175f * 0.70710678f; // MOTOR_DIST / sqrt(2)
constexpr float JXY       = 0.0023f;
constexpr float JZ        = 0.004f;
constexpr float INV_JXY   = 1.0f / 0.0023f;
constexpr float INV_JZ    = 1.0f / 0.004f;
constexpr float G3        = -9.81f;
constexpr float INV_L     = 2.0f;
constexpr float DT        = 0.05f;
constexpr float DT2       = 0.05f * 0.5f;
constexpr float DT6       = 0.05f / 6.0f;

// Packed (2 rows/lane) dynamics. FzM = Fz/MASS precomputed (stage-invariant).
__device__ __forceinline__ void dyn2(const vf2* xt, vf2 FzM,
                                     vf2 taux, vf2 tauy, vf2 tauz, vf2* dx) {
  vf2 mx = xt[3], my = xt[4], mz = xt[5], th = xt[6];
  vf2 vx = xt[7], vy = xt[8], vz = xt[9];
  vf2 wx = xt[10], wy = xt[11], wz = xt[12];

  vf2 n2 = mx * mx + my * my + mz * mz;
  vf2 inv;
  inv.x = __builtin_amdgcn_rcpf(1.0f + n2.x);
  inv.y = __builtin_amdgcn_rcpf(1.0f + n2.y);
  vf2 s  = (sp(1.0f) - n2) * inv;
  vf2 qx = sp(2.0f) * mx * inv;
  vf2 qy = sp(2.0f) * my * inv;
  vf2 qz = sp(2.0f) * mz * inv;

  // gravity rotation quatrot(-q, (0,0,g)) hand-specialized (exact: dropped
  // terms are *0.0); g applied directly (MASS*g/MASS folded).
  vf2 gtx = qy * sp(-G3);
  vf2 gty = qx * sp(G3);
  vf2 gtz = s * sp(G3);
  vf2 gx = sp(-2.0f) * (qy * gtz - qz * gty);
  vf2 gy = sp(-2.0f) * (qz * gtx - qx * gtz);
  vf2 gz = sp(G3) + sp(-2.0f) * (qx * gty - qy * gtx);

  // pdot = quatrot(q, v)
  vf2 tx = qy * vz - qz * vy + s * vx;
  vf2 ty = qz * vx - qx * vz + s * vy;
  vf2 tz = qx * vy - qy * vx + s * vz;
  dx[0] = vx + sp(2.0f) * (qy * tz - qz * ty);
  dx[1] = vy + sp(2.0f) * (qz * tx - qx * tz);
  dx[2] = vz + sp(2.0f) * (qx * ty - qy * tx);

  // mdot
  vf2 mw  = mx * wx + my * wy + mz * wz;
  vf2 on2 = sp(1.0f) - n2;
  dx[3] = sp(0.25f) * (on2 * wx + sp(2.0f) * (my * wz - mz * wy) + sp(2.0f) * mx * mw);
  dx[4] = sp(0.25f) * (on2 * wy + sp(2.0f) * (mz * wx - mx * wz) + sp(2.0f) * my * mw);
  dx[5] = sp(0.25f) * (on2 * wz + sp(2.0f) * (mx * wy - my * wx) + sp(2.0f) * mz * mw);

  dx[6] = xt[13];

  // vdot = (0,0,Fz/M) + g' - w x v
  vf2 vdx = gx - (wy * vz - wz * vy);
  vf2 vdy = gy - (wz * vx - wx * vz);
  vf2 vdz = FzM + gz - (wx * vy - wy * vx);
  dx[7] = vdx; dx[8] = vdy; dx[9] = vdz;

  // wdot
  vf2 Jwx = sp(JXY) * wx, Jwy = sp(JXY) * wy, Jwz = sp(JZ) * wz;
  dx[10] = (taux - (wy * Jwz - wz * Jwy)) * sp(INV_JXY);
  dx[11] = (tauy - (wz * Jwx - wx * Jwz)) * sp(INV_JXY);
  dx[12] = (tauz - (wx * Jwy - wy * Jwx)) * sp(INV_JZ);

  // x_ddot = quatrot(q, vdot).x only
  vf2 t2y = qz * vdx - qx * vdz + s * vdy;
  vf2 t2z = qx * vdy - qy * vdx + s * vdz;
  vf2 rx  = vdx + sp(2.0f) * (qy * t2z - qz * t2y);
  vf2 st, ct;
  st.x = __sinf(th.x); st.y = __sinf(th.y);
  ct.x = __cosf(th.x); ct.y = __cosf(th.y);
  dx[13] = (sp(G3) * st + rx * ct) * sp(INV_L);
}

__device__ __forceinline__ void rk4_rows2(const vf2* x0, vf4 uA, vf4 uB, vf2* o) {
  vf2 su0 = sp(ACT_SCALE) * (vf2{uA.x, uB.x} + sp(U_HOVER));
  vf2 su1 = sp(ACT_SCALE) * (vf2{uA.y, uB.y} + sp(U_HOVER));
  vf2 su2 = sp(ACT_SCALE) * (vf2{uA.z, uB.z} + sp(U_HOVER));
  vf2 su3 = sp(ACT_SCALE) * (vf2{uA.w, uB.w} + sp(U_HOVER));

  vf2 Fz   = ((su0 + su1) + su2) + su3;
  vf2 FzM  = Fz * sp(INV_MASS);
  vf2 tauz = sp(KM) * (((su0 - su1) + su2) - su3);
  vf2 taux = ((sp(TAUC) * su0 + sp(-TAUC) * su1) + sp(-TAUC) * su2) + sp(TAUC) * su3;
  vf2 tauy = ((sp(-TAUC) * su0 + sp(-TAUC) * su1) + sp(TAUC) * su2) + sp(TAUC) * su3;

  vf2 xt[14], kk[14], acc[14];
  dyn2(x0, FzM, taux, tauy, tauz, kk);
  #pragma unroll
  for (int j = 0; j < 14; ++j) { acc[j] = kk[j]; xt[j] = x0[j] + sp(DT2) * kk[j]; }
  dyn2(xt, FzM, taux, tauy, tauz, kk);
  #pragma unroll
  for (int j = 0; j < 14; ++j) { acc[j] += sp(2.0f) * kk[j]; xt[j] = x0[j] + sp(DT2) * kk[j]; }
  dyn2(xt, FzM, taux, tauy, tauz, kk);
  #pragma unroll
  for (int j = 0; j < 14; ++j) { acc[j] += sp(2.0f) * kk[j]; xt[j] = x0[j] + sp(DT) * kk[j]; }
  dyn2(xt, FzM, taux, tauy, tauz, kk);
  #pragma unroll
  for (int j = 0; j < 14; ++j) o[j] = x0[j] + sp(DT6) * (acc[j] + kk[j]);
}

// Persistent grid-strided worker with register prefetch of the next tile
// (T14 async-stage): HBM latency of tile T+1 hides under RK4 of tile T.
// Memory shape unchanged from R8: coalesced vf4 <-> LDS both directions,
// thread owns adjacent rows 2t,2t+1 (28 contiguous LDS words).
__global__ __launch_bounds__(256) void fc_rk4_kernel(const float* __restrict__ x,
                                                     const float* __restrict__ u,
                                                     float* __restrict__ out,
                                                     int n, int nfull) {
  __shared__ float xs[512 * 14];  // 28672 B
  const int t = threadIdx.x;
  const int stride = gridDim.x;
  int tile = blockIdx.x;

  if (tile < nfull) {
    vf4 r0, r1, r2, r3, r4, r5, r6, uA, uB;
    {  // prologue prefetch
      const vf4* xg4 = (const vf4*)(x + (long long)tile * 512 * 14);
      r0 = __builtin_nontemporal_load(xg4 + t);
      r1 = __builtin_nontemporal_load(xg4 + t + 256);
      r2 = __builtin_nontemporal_load(xg4 + t + 512);
      r3 = __builtin_nontemporal_load(xg4 + t + 768);
      r4 = __builtin_nontemporal_load(xg4 + t + 1024);
      r5 = __builtin_nontemporal_load(xg4 + t + 1280);
      r6 = __builtin_nontemporal_load(xg4 + t + 1536);
      const vf4* ug = (const vf4*)(u + (long long)tile * 512 * 4) + 2 * t;
      uA = ug[0]; uB = ug[1];
    }
    while (true) {
      // ---- stage-in current tile from regs (coalesced linear) ----
      vf4* xs4 = (vf4*)xs;
      xs4[t]        = r0;
      xs4[t + 256]  = r1;
      xs4[t + 512]  = r2;
      xs4[t + 768]  = r3;
      xs4[t + 1024] = r4;
      xs4[t + 1280] = r5;
      xs4[t + 1536] = r6;
      __syncthreads();

      // ---- issue next-tile prefetch (results consumed only after compute) ----
      const int next = tile + stride;
      const bool have_next = next < nfull;
      vf4 p0, p1, p2, p3, p4, p5, p6, uAn, uBn;
      if (have_next) {
        const vf4* xg4 = (const vf4*)(x + (long long)next * 512 * 14);
        p0 = __builtin_nontemporal_load(xg4 + t);
        p1 = __builtin_nontemporal_load(xg4 + t + 256);
        p2 = __builtin_nontemporal_load(xg4 + t + 512);
        p3 = __builtin_nontemporal_load(xg4 + t + 768);
        p4 = __builtin_nontemporal_load(xg4 + t + 1024);
        p5 = __builtin_nontemporal_load(xg4 + t + 1280);
        p6 = __builtin_nontemporal_load(xg4 + t + 1536);
        const vf4* ug = (const vf4*)(u + (long long)next * 512 * 4) + 2 * t;
        uAn = ug[0]; uBn = ug[1];
      }

      // ---- own-rows gather: 7x ds_read_b128 ----
      vf4* mine = (vf4*)(xs + t * 28);
      vf4 a0 = mine[0], a1 = mine[1], a2 = mine[2], a3 = mine[3],
          a4 = mine[4], a5 = mine[5], a6 = mine[6];
      vf2 x0[14] = {
        {a0.x, a3.z}, {a0.y, a3.w}, {a0.z, a4.x}, {a0.w, a4.y},
        {a1.x, a4.z}, {a1.y, a4.w}, {a1.z, a5.x}, {a1.w, a5.y},
        {a2.x, a5.z}, {a2.y, a5.w}, {a2.z, a6.x}, {a2.w, a6.y},
        {a3.x, a6.z}, {a3.y, a6.w}};

      vf2 o[14];
      rk4_rows2(x0, uA, uB, o);

      // ---- write back own rows ----
      mine[0] = vf4{o[0].x,  o[1].x,  o[2].x,  o[3].x};
      mine[1] = vf4{o[4].x,  o[5].x,  o[6].x,  o[7].x};
      mine[2] = vf4{o[8].x,  o[9].x,  o[10].x, o[11].x};
      mine[3] = vf4{o[12].x, o[13].x, o[0].y,  o[1].y};
      mine[4] = vf4{o[2].y,  o[3].y,  o[4].y,  o[5].y};
      mine[5] = vf4{o[6].y,  o[7].y,  o[8].y,  o[9].y};
      mine[6] = vf4{o[10].y, o[11].y, o[12].y, o[13].y};
      __syncthreads();

      // ---- coalesced nontemporal drain ----
      vf4* og4 = (vf4*)(out + (long long)tile * 512 * 14);
      __builtin_nontemporal_store(xs4[t],        og4 + t);
      __builtin_nontemporal_store(xs4[t + 256],  og4 + t + 256);
      __builtin_nontemporal_store(xs4[t + 512],  og4 + t + 512);
      __builtin_nontemporal_store(xs4[t + 768],  og4 + t + 768);
      __builtin_nontemporal_store(xs4[t + 1024], og4 + t + 1024);
      __builtin_nontemporal_store(xs4[t + 1280], og4 + t + 1280);
      __builtin_nontemporal_store(xs4[t + 1536], og4 + t + 1536);

      if (!have_next) break;
      tile = next;
      r0 = p0; r1 = p1; r2 = p2; r3 = p3; r4 = p4; r5 = p5; r6 = p6;
      uA = uAn; uB = uBn;
      __syncthreads();  // WAR: drain reads done (pre-store lgkmcnt) before overwrite
    }
  }

  // ---- tail rows (n % 512), block 0 only; not hit at B=2M ----
  const long long tbase = (long long)nfull * 512;
  if (blockIdx.x == 0 && tbase < n) {
    #pragma unroll
    for (int k = 0; k < 2; ++k) {
      long long rrow = tbase + 2LL * t + k;
      if (rrow < n) {
        vf2 x0[14];
        #pragma unroll
        for (int j = 0; j < 14; ++j) { float v = x[rrow * 14 + j]; x0[j] = vf2{v, v}; }
        vf4 uv = *(const vf4*)(u + rrow * 4);
        vf2 o[14];
        rk4_rows2(x0, uv, uv, o);
        #pragma unroll
        for (int j = 0; j < 14; ++j) out[rrow * 14 + j] = o[j].x;
      }
    }
  }
}

}  // namespace fc

extern "C" void kernel_launch(void* const* d_in, const int* in_sizes, int n_in,
                              void* d_out, int out_size, void* d_ws, size_t ws_size,
                              hipStream_t stream) {
  const float* x = (const float*)d_in[0];
  const float* u = (const float*)d_in[1];
  float* out = (float*)d_out;
  const int n = in_sizes[0] / 14;
  const int nfull = n / 512;
  int grid = nfull < 1024 ? (nfull > 0 ? nfull : 1) : 1024;  // 4/CU, 4096/1024 = 4 tiles each
  hipLaunchKernelGGL(fc::fc_rk4_kernel, dim3(grid), dim3(256), 0, stream,
                     x, u, out, n, nfull);
}

// Round 10
// 45.550 us; speedup vs baseline: 1.1572x; 1.1572x over previous
//
#include <hip/hip_runtime.h>
#include <math.h>

namespace fc {

typedef float vf2 __attribute__((ext_vector_type(2)));
typedef float vf4 __attribute__((ext_vector_type(4)));

__device__ __forceinline__ vf2 sp(float c) { return vf2{c, c}; }

constexpr float ACT_SCALE = 10.0f;
constexpr float U_HOVER   = 0.515025f;          // -MASS*-9.81/10/1/4
constexpr float INV_MASS  = 1.0f / 2.1f;
constexpr float KM        = 0.025f;
constexpr float TAUC      = 0.175f * 0.70710678f; // MOTOR_DIST / sqrt(2)
constexpr float JXY       = 0.0023f;
constexpr float JZ        = 0.004f;
constexpr float INV_JXY   = 1.0f / 0.0023f;
constexpr float INV_JZ    = 1.0f / 0.004f;
constexpr float G3        = -9.81f;
constexpr float INV_L     = 2.0f;
constexpr float DT        = 0.05f;
constexpr float DT2       = 0.05f * 0.5f;
constexpr float DT6       = 0.05f / 6.0f;

// Packed (2 rows/lane) dynamics. FzM = Fz/MASS precomputed (stage-invariant).
__device__ __forceinline__ void dyn2(const vf2* xt, vf2 FzM,
                                     vf2 taux, vf2 tauy, vf2 tauz, vf2* dx) {
  vf2 mx = xt[3], my = xt[4], mz = xt[5], th = xt[6];
  vf2 vx = xt[7], vy = xt[8], vz = xt[9];
  vf2 wx = xt[10], wy = xt[11], wz = xt[12];

  vf2 n2 = mx * mx + my * my + mz * mz;
  vf2 inv;
  inv.x = __builtin_amdgcn_rcpf(1.0f + n2.x);
  inv.y = __builtin_amdgcn_rcpf(1.0f + n2.y);
  vf2 s  = (sp(1.0f) - n2) * inv;
  vf2 qx = sp(2.0f) * mx * inv;
  vf2 qy = sp(2.0f) * my * inv;
  vf2 qz = sp(2.0f) * mz * inv;

  // gravity rotation quatrot(-q, (0,0,g)) hand-specialized (exact: dropped
  // terms are *0.0); g applied directly (MASS*g/MASS folded).
  vf2 gtx = qy * sp(-G3);
  vf2 gty = qx * sp(G3);
  vf2 gtz = s * sp(G3);
  vf2 gx = sp(-2.0f) * (qy * gtz - qz * gty);
  vf2 gy = sp(-2.0f) * (qz * gtx - qx * gtz);
  vf2 gz = sp(G3) + sp(-2.0f) * (qx * gty - qy * gtx);

  // pdot = quatrot(q, v)
  vf2 tx = qy * vz - qz * vy + s * vx;
  vf2 ty = qz * vx - qx * vz + s * vy;
  vf2 tz = qx * vy - qy * vx + s * vz;
  dx[0] = vx + sp(2.0f) * (qy * tz - qz * ty);
  dx[1] = vy + sp(2.0f) * (qz * tx - qx * tz);
  dx[2] = vz + sp(2.0f) * (qx * ty - qy * tx);

  // mdot
  vf2 mw  = mx * wx + my * wy + mz * wz;
  vf2 on2 = sp(1.0f) - n2;
  dx[3] = sp(0.25f) * (on2 * wx + sp(2.0f) * (my * wz - mz * wy) + sp(2.0f) * mx * mw);
  dx[4] = sp(0.25f) * (on2 * wy + sp(2.0f) * (mz * wx - mx * wz) + sp(2.0f) * my * mw);
  dx[5] = sp(0.25f) * (on2 * wz + sp(2.0f) * (mx * wy - my * wx) + sp(2.0f) * mz * mw);

  dx[6] = xt[13];

  // vdot = (0,0,Fz/M) + g' - w x v
  vf2 vdx = gx - (wy * vz - wz * vy);
  vf2 vdy = gy - (wz * vx - wx * vz);
  vf2 vdz = FzM + gz - (wx * vy - wy * vx);
  dx[7] = vdx; dx[8] = vdy; dx[9] = vdz;

  // wdot
  vf2 Jwx = sp(JXY) * wx, Jwy = sp(JXY) * wy, Jwz = sp(JZ) * wz;
  dx[10] = (taux - (wy * Jwz - wz * Jwy)) * sp(INV_JXY);
  dx[11] = (tauy - (wz * Jwx - wx * Jwz)) * sp(INV_JXY);
  dx[12] = (tauz - (wx * Jwy - wy * Jwx)) * sp(INV_JZ);

  // x_ddot = quatrot(q, vdot).x only
  vf2 t2y = qz * vdx - qx * vdz + s * vdy;
  vf2 t2z = qx * vdy - qy * vdx + s * vdz;
  vf2 rx  = vdx + sp(2.0f) * (qy * t2z - qz * t2y);
  vf2 st, ct;
  st.x = __sinf(th.x); st.y = __sinf(th.y);
  ct.x = __cosf(th.x); ct.y = __cosf(th.y);
  dx[13] = (sp(G3) * st + rx * ct) * sp(INV_L);
}

__device__ __forceinline__ void rk4_rows2(const vf2* x0, vf4 uA, vf4 uB, vf2* o) {
  vf2 su0 = sp(ACT_SCALE) * (vf2{uA.x, uB.x} + sp(U_HOVER));
  vf2 su1 = sp(ACT_SCALE) * (vf2{uA.y, uB.y} + sp(U_HOVER));
  vf2 su2 = sp(ACT_SCALE) * (vf2{uA.z, uB.z} + sp(U_HOVER));
  vf2 su3 = sp(ACT_SCALE) * (vf2{uA.w, uB.w} + sp(U_HOVER));

  vf2 Fz   = ((su0 + su1) + su2) + su3;
  vf2 FzM  = Fz * sp(INV_MASS);
  vf2 tauz = sp(KM) * (((su0 - su1) + su2) - su3);
  vf2 taux = ((sp(TAUC) * su0 + sp(-TAUC) * su1) + sp(-TAUC) * su2) + sp(TAUC) * su3;
  vf2 tauy = ((sp(-TAUC) * su0 + sp(-TAUC) * su1) + sp(TAUC) * su2) + sp(TAUC) * su3;

  vf2 xt[14], kk[14], acc[14];
  dyn2(x0, FzM, taux, tauy, tauz, kk);
  #pragma unroll
  for (int j = 0; j < 14; ++j) { acc[j] = kk[j]; xt[j] = x0[j] + sp(DT2) * kk[j]; }
  dyn2(xt, FzM, taux, tauy, tauz, kk);
  #pragma unroll
  for (int j = 0; j < 14; ++j) { acc[j] += sp(2.0f) * kk[j]; xt[j] = x0[j] + sp(DT2) * kk[j]; }
  dyn2(xt, FzM, taux, tauy, tauz, kk);
  #pragma unroll
  for (int j = 0; j < 14; ++j) { acc[j] += sp(2.0f) * kk[j]; xt[j] = x0[j] + sp(DT) * kk[j]; }
  dyn2(xt, FzM, taux, tauy, tauz, kk);
  #pragma unroll
  for (int j = 0; j < 14; ++j) o[j] = x0[j] + sp(DT6) * (acc[j] + kk[j]);
}

// ZERO-BARRIER version: each wave owns a contiguous 128-row region (7168 B).
// Stage-in is direct global->LDS (global_load_lds width=16: linear dest =
// wave-uniform base + lane*16 matches our layout exactly); waits are
// wave-local (vmcnt/lgkmcnt), so waves drift freely and memory of some waves
// overlaps compute of others. Global access stays perfectly coalesced.
__global__ __launch_bounds__(256) void fc_rk4_kernel(const float* __restrict__ x,
                                                     const float* __restrict__ u,
                                                     float* __restrict__ out,
                                                     int n) {
  __shared__ float xs[512 * 14];  // 4 waves x 1792 words
  const int t = threadIdx.x;
  const int lane = t & 63;
  const int w = t >> 6;
  const long long base = (long long)blockIdx.x * 512;

  if (base + 512 <= (long long)n) {
    const long long wrow = base + w * 128;      // this wave's 128 rows
    float* ws = xs + w * 1792;                  // this wave's LDS region

    // ---- direct global->LDS staging: 7x global_load_lds_dwordx4 ----
    typedef __attribute__((address_space(3))) float lds_f;
    typedef const __attribute__((address_space(1))) float gbl_f;
    gbl_f* gsrc = (gbl_f*)(x + wrow * 14);
    lds_f* ldst = (lds_f*)ws;
    #pragma unroll
    for (int k = 0; k < 7; ++k)
      __builtin_amdgcn_global_load_lds(
          (const __attribute__((address_space(1))) void*)(gsrc + k * 256 + lane * 4),
          (__attribute__((address_space(3))) void*)(ldst + k * 256), 16, 0, 0);

    // u rows for this lane's pair (issued while staging is in flight)
    const vf4* ug = (const vf4*)(u + wrow * 4);
    vf4 uA = ug[2 * lane];
    vf4 uB = ug[2 * lane + 1];

    asm volatile("s_waitcnt vmcnt(0)" ::: "memory");  // wave-local stall only

    // ---- own-rows gather: 7x ds_read_b128, word-stride 28 (conflict-free) ----
    vf4* mine = (vf4*)(ws + lane * 28);
    vf4 a0 = mine[0], a1 = mine[1], a2 = mine[2], a3 = mine[3],
        a4 = mine[4], a5 = mine[5], a6 = mine[6];
    vf2 x0[14] = {
      {a0.x, a3.z}, {a0.y, a3.w}, {a0.z, a4.x}, {a0.w, a4.y},
      {a1.x, a4.z}, {a1.y, a4.w}, {a1.z, a5.x}, {a1.w, a5.y},
      {a2.x, a5.z}, {a2.y, a5.w}, {a2.z, a6.x}, {a2.w, a6.y},
      {a3.x, a6.z}, {a3.y, a6.w}};

    vf2 o[14];
    rk4_rows2(x0, uA, uB, o);

    // ---- write back own rows: 7x ds_write_b128 ----
    mine[0] = vf4{o[0].x,  o[1].x,  o[2].x,  o[3].x};
    mine[1] = vf4{o[4].x,  o[5].x,  o[6].x,  o[7].x};
    mine[2] = vf4{o[8].x,  o[9].x,  o[10].x, o[11].x};
    mine[3] = vf4{o[12].x, o[13].x, o[0].y,  o[1].y};
    mine[4] = vf4{o[2].y,  o[3].y,  o[4].y,  o[5].y};
    mine[5] = vf4{o[6].y,  o[7].y,  o[8].y,  o[9].y};
    mine[6] = vf4{o[10].y, o[11].y, o[12].y, o[13].y};
    asm volatile("s_waitcnt lgkmcnt(0)" ::: "memory");  // wave-local

    // ---- coalesced nontemporal drain of wave region ----
    const vf4* ws4 = (const vf4*)ws;
    vf4* og4 = (vf4*)(out + wrow * 14);
    #pragma unroll
    for (int k = 0; k < 7; ++k)
      __builtin_nontemporal_store(ws4[k * 64 + lane], og4 + k * 64 + lane);
  } else {
    // tail (not hit at B=2M): per-row scalar path, row duplicated in both lanes
    #pragma unroll
    for (int k = 0; k < 2; ++k) {
      long long r = base + 2LL * t + k;
      if (r < n) {
        vf2 x0[14];
        #pragma unroll
        for (int j = 0; j < 14; ++j) { float v = x[r * 14 + j]; x0[j] = vf2{v, v}; }
        vf4 uv = *(const vf4*)(u + r * 4);
        vf2 o[14];
        rk4_rows2(x0, uv, uv, o);
        #pragma unroll
        for (int j = 0; j < 14; ++j) out[r * 14 + j] = o[j].x;
      }
    }
  }
}

}  // namespace fc

extern "C" void kernel_launch(void* const* d_in, const int* in_sizes, int n_in,
                              void* d_out, int out_size, void* d_ws, size_t ws_size,
                              hipStream_t stream) {
  const float* x = (const float*)d_in[0];
  const float* u = (const float*)d_in[1];
  float* out = (float*)d_out;
  const int n = in_sizes[0] / 14;
  const int grid = (n + 511) / 512;
  hipLaunchKernelGGL(fc::fc_rk4_kernel, dim3(grid), dim3(256), 0, stream,
                     x, u, out, n);
}